// Round 1
// baseline (2242.362 us; speedup 1.0000x reference)
//
#include <hip/hip_runtime.h>
#include <hip/hip_bf16.h>
#include <math.h>

#define NN 4096
#define DD 64
#define KK 15
#define NNEG_ 32
#define TEMP_INV 10.0f
#define NEGINF -1e30f

// accumulator slots
#define A_ALIGN 0
#define A_ATTR  1
#define A_REP   2
#define A_LAPA  3
#define A_LAPB  4
#define A_S2    5
#define A_CROSS 6
#define A_A2    7

__device__ __forceinline__ float waveReduceSum(float v) {
  #pragma unroll
  for (int m = 32; m >= 1; m >>= 1) v += __shfl_xor(v, m, 64);
  return v;
}

__global__ void k_init(float* acc) {
  if (threadIdx.x < 16) acc[threadIdx.x] = 0.f;
}

// one wave per row: L2-normalize; for atac also record raw norm and Sum(z^2)
__global__ void k_norm(const float* __restrict__ Z, float* __restrict__ Zn,
                       float* __restrict__ norms, float* __restrict__ acc, int isAtac) {
  int row = blockIdx.x * 4 + (threadIdx.x >> 6);
  int lane = threadIdx.x & 63;
  float v = Z[row * DD + lane];
  float s = waveReduceSum(v * v);
  float nrm = sqrtf(s);
  Zn[row * DD + lane] = v / fmaxf(nrm, 1e-12f);
  if (isAtac && lane == 0) {
    norms[row] = nrm;
    atomicAdd(&acc[A_LAPA], s);
  }
}

// 2 rows per block (128 threads = 2 waves). Computes full sim row in LDS,
// repeated argmax top-15 (tie -> lower index, matching lax.top_k), softmax/TEMP.
__global__ __launch_bounds__(128) void k_topk(const float* __restrict__ Zn,
    int* __restrict__ oidx, float* __restrict__ ow, float* __restrict__ acc, int doA2) {
  __shared__ __align__(16) float zi[2][DD];
  __shared__ float sb[2][NN];
  __shared__ float topv[2][KK];
  __shared__ int   topi[2][KK];
  int tid = threadIdx.x;
  int row0 = blockIdx.x * 2;
  { int r = tid >> 6, d = tid & 63; zi[r][d] = Zn[(row0 + r) * DD + d]; }
  __syncthreads();
  for (int j = tid; j < NN; j += 128) {
    const float4* zp = (const float4*)(Zn + (size_t)j * DD);
    float d0 = 0.f, d1 = 0.f;
    #pragma unroll
    for (int c = 0; c < DD / 4; ++c) {
      float4 q = zp[c];
      float4 a0 = ((const float4*)zi[0])[c];
      float4 a1 = ((const float4*)zi[1])[c];
      d0 += q.x * a0.x + q.y * a0.y + q.z * a0.z + q.w * a0.w;
      d1 += q.x * a1.x + q.y * a1.y + q.z * a1.z + q.w * a1.w;
    }
    sb[0][j] = d0; sb[1][j] = d1;
  }
  __syncthreads();
  if (tid < 2) sb[tid][row0 + tid] = NEGINF;   // mask diagonal
  __syncthreads();
  int w = tid >> 6, lane = tid & 63;
  float* s = sb[w];
  for (int t = 0; t < KK; ++t) {
    float best = -3e38f; int bi = 0;
    for (int c = lane; c < NN; c += 64) {
      float x = s[c];
      if (x > best) { best = x; bi = c; }
    }
    #pragma unroll
    for (int m = 32; m >= 1; m >>= 1) {
      float ov = __shfl_xor(best, m, 64);
      int   oi = __shfl_xor(bi, m, 64);
      if (ov > best || (ov == best && oi < bi)) { best = ov; bi = oi; }
    }
    if (lane == (bi & 63)) s[bi] = NEGINF;  // extractor lane == re-reader lane
    if (lane == 0) { topv[w][t] = best; topi[w][t] = bi; }
  }
  if (lane == 0) {
    float m = topv[w][0];            // first extracted is the max
    float e[KK]; float sum = 0.f;
    for (int t = 0; t < KK; ++t) { e[t] = expf((topv[w][t] - m) * TEMP_INV); sum += e[t]; }
    float a2 = 0.f;
    int grow = row0 + w;
    for (int t = 0; t < KK; ++t) {
      float wv = e[t] / sum;
      ow[grow * KK + t] = wv;
      oidx[grow * KK + t] = topi[w][t];
      a2 += wv * wv;
    }
    if (doA2) atomicAdd(&acc[A_A2], a2);
  }
}

// one wave per row: align (KL on rna support), attr, lapB = Sum <z_i,z_j> on support
__global__ void k_edges(const float* __restrict__ Zan, const float* __restrict__ norms,
    const int* __restrict__ ridx, const float* __restrict__ rw,
    const int* __restrict__ aidx, const float* __restrict__ aw,
    float* __restrict__ acc) {
  int w = threadIdx.x >> 6, lane = threadIdx.x & 63;
  int i = blockIdx.x * 4 + w;
  float zi = Zan[i * DD + lane];
  float alignAcc = 0.f, attrAcc = 0.f, lapBAcc = 0.f;
  float normi = norms[i];
  for (int t = 0; t < KK; ++t) {
    int j = ridx[i * KK + t];
    float tw = rw[i * KK + t];
    float zj = Zan[j * DD + lane];
    float dot = waveReduceSum(zi * zj);
    if (lane == 0) {
      attrAcc += 1.f - dot;
      lapBAcc += normi * norms[j] * dot;
      float aval = 0.f;
      for (int t2 = 0; t2 < KK; ++t2)
        if (aidx[i * KK + t2] == j) aval = aw[i * KK + t2];
      if (tw > 0.f) alignAcc += tw * (logf(tw) - logf(aval + 1e-8f));
    }
  }
  if (lane == 0) {
    atomicAdd(&acc[A_ALIGN], alignAcc);
    atomicAdd(&acc[A_ATTR], attrAcc);
    atomicAdd(&acc[A_LAPB], lapBAcc);
  }
}

// one block per row: top-32 of masked noise, then rep = Sum relu(dot-0.5)
__global__ __launch_bounds__(256) void k_neg(const float* __restrict__ noise,
    const float* __restrict__ Zan, const int* __restrict__ ridx, float* __restrict__ acc) {
  __shared__ float nb[NN];
  __shared__ float rv[256];
  __shared__ int   ri[256];
  __shared__ int   sel[NNEG_];
  __shared__ float zi[DD];
  int tid = threadIdx.x;
  int i = blockIdx.x;
  for (int c = tid; c < NN; c += 256) nb[c] = noise[(size_t)i * NN + c];
  if (tid < DD) zi[tid] = Zan[i * DD + tid];
  __syncthreads();
  if (tid == 0) nb[i] = -1.f;
  if (tid < KK) nb[ridx[i * KK + tid]] = -1.f;
  __syncthreads();
  for (int t = 0; t < NNEG_; ++t) {
    float best = -3.f; int bi = 0;
    for (int c = tid; c < NN; c += 256) {
      float x = nb[c];
      if (x > best) { best = x; bi = c; }
    }
    rv[tid] = best; ri[tid] = bi;
    __syncthreads();
    for (int sN = 128; sN >= 1; sN >>= 1) {
      if (tid < sN) {
        float ov = rv[tid + sN]; int oi = ri[tid + sN];
        if (ov > rv[tid] || (ov == rv[tid] && oi < ri[tid])) { rv[tid] = ov; ri[tid] = oi; }
      }
      __syncthreads();
    }
    if (tid == 0) { sel[t] = ri[0]; nb[ri[0]] = -2.f; }
    __syncthreads();
  }
  float part = 0.f;
  if (tid < NNEG_) {
    int j = sel[tid];
    const float* zj = Zan + (size_t)j * DD;
    float dot = 0.f;
    #pragma unroll
    for (int d = 0; d < DD; ++d) dot += zi[d] * zj[d];
    part = fmaxf(dot - 0.5f, 0.f);   // relu(MARGIN - (1-dot))
  }
  rv[tid] = part;
  __syncthreads();
  for (int sN = 128; sN >= 1; sN >>= 1) {
    if (tid < sN) rv[tid] += rv[tid + sN];
    __syncthreads();
  }
  if (tid == 0) atomicAdd(&acc[A_REP], rv[0]);
}

__global__ void k_zero(float4* p, int n4) {
  int i = blockIdx.x * blockDim.x + threadIdx.x;
  if (i < n4) p[i] = make_float4(0.f, 0.f, 0.f, 0.f);
}

// S0 = A_rna_soft restricted to column block [c0, c0+B)
__global__ void k_scatter(float* __restrict__ S, const int* __restrict__ ridx,
                          const float* __restrict__ rw, int c0, int B) {
  int w = threadIdx.x >> 6, lane = threadIdx.x & 63;
  int i = blockIdx.x * 4 + w;
  if (lane < KK) {
    int j = ridx[i * KK + lane] - c0;
    if (j >= 0 && j < B) S[(size_t)i * B + j] = rw[i * KK + lane];
  }
}

// S_next[i,:] = 0.8 * Sum_t w_t * S_cur[j_t,:] + 0.2 * A[i,:]  (column block)
__global__ __launch_bounds__(256) void k_spmm(const float* __restrict__ Scur,
    float* __restrict__ Snext, const int* __restrict__ ridx,
    const float* __restrict__ rw, int c0, int B) {
  __shared__ int nj[KK]; __shared__ float nw[KK];
  int i = blockIdx.x; int tid = threadIdx.x;
  if (tid < KK) { nj[tid] = ridx[i * KK + tid]; nw[tid] = rw[i * KK + tid]; }
  __syncthreads();
  for (int c = tid * 4; c < B; c += 1024) {
    float ax = 0.f, ay = 0.f, az = 0.f, aw4 = 0.f;
    #pragma unroll
    for (int t = 0; t < KK; ++t) {
      const float4 sv = *(const float4*)(Scur + (size_t)nj[t] * B + c);
      float wv = nw[t];
      ax += wv * sv.x; ay += wv * sv.y; az += wv * sv.z; aw4 += wv * sv.w;
    }
    ax *= 0.8f; ay *= 0.8f; az *= 0.8f; aw4 *= 0.8f;
    #pragma unroll
    for (int t = 0; t < KK; ++t) {
      int rc = nj[t] - c0 - c;
      float v = 0.2f * nw[t];
      if (rc == 0) ax += v; else if (rc == 1) ay += v;
      else if (rc == 2) az += v; else if (rc == 3) aw4 += v;
    }
    float4 o; o.x = ax; o.y = ay; o.z = az; o.w = aw4;
    *(float4*)(Snext + (size_t)i * B + c) = o;
  }
}

__global__ void k_vinit(const float* __restrict__ rw, float* __restrict__ r,
                        float* __restrict__ va) {
  int i = blockIdx.x * 256 + threadIdx.x;
  float s = 0.f;
  #pragma unroll
  for (int t = 0; t < KK; ++t) s += rw[i * KK + t];
  r[i] = s; va[i] = s;
}

__global__ void k_vstep(const float* __restrict__ va, float* __restrict__ vb,
    const float* __restrict__ r, const int* __restrict__ ridx,
    const float* __restrict__ rw) {
  int i = blockIdx.x * 256 + threadIdx.x;
  float s = 0.f;
  #pragma unroll
  for (int t = 0; t < KK; ++t) s += rw[i * KK + t] * va[ridx[i * KK + t]];
  vb[i] = 0.8f * s + 0.2f * r[i];
}

// Sum over block of (S/rowsum)^2
__global__ __launch_bounds__(256) void k_s2(const float* __restrict__ S,
    const float* __restrict__ v, float* __restrict__ acc, int B) {
  __shared__ float red[256];
  int i = blockIdx.x; int tid = threadIdx.x;
  float inv = 1.f / fmaxf(v[i], 1e-8f);
  float s = 0.f;
  for (int c = tid; c < B; c += 256) { float x = S[(size_t)i * B + c] * inv; s += x * x; }
  red[tid] = s; __syncthreads();
  for (int sN = 128; sN >= 1; sN >>= 1) {
    if (tid < sN) red[tid] += red[tid + sN];
    __syncthreads();
  }
  if (tid == 0) atomicAdd(&acc[A_S2], red[0]);
}

// Sum over atac support of a_ij * (S/rowsum)_ij for cols in block
__global__ void k_cross(const float* __restrict__ S, const float* __restrict__ v,
    const int* __restrict__ aidx, const float* __restrict__ aw,
    float* __restrict__ acc, int c0, int B) {
  int w = threadIdx.x >> 6, lane = threadIdx.x & 63;
  int i = blockIdx.x * 4 + w;
  float part = 0.f;
  if (lane < KK) {
    int j = aidx[i * KK + lane] - c0;
    if (j >= 0 && j < B)
      part = aw[i * KK + lane] * S[(size_t)i * B + j] / fmaxf(v[i], 1e-8f);
  }
  part = waveReduceSum(part);
  if (lane == 0) atomicAdd(&acc[A_CROSS], part);
}

__global__ void k_final(const float* __restrict__ acc, float* __restrict__ out) {
  float alignv = acc[A_ALIGN] / (float)NN;
  float attr = acc[A_ATTR] / (15.f * (float)NN);
  float rep = acc[A_REP] / ((float)NN * (float)NNEG_);
  float lap = (acc[A_LAPA] - acc[A_LAPB] / 15.f) / (float)NN;
  float diff = (acc[A_S2] - 2.f * acc[A_CROSS] + acc[A_A2]) / ((float)NN * (float)NN);
  out[0] = alignv + (attr + rep) + 0.5f * lap + 0.5f * diff;
}

extern "C" void kernel_launch(void* const* d_in, const int* in_sizes, int n_in,
                              void* d_out, int out_size, void* d_ws, size_t ws_size,
                              hipStream_t stream) {
  const float* z_rna  = (const float*)d_in[0];
  const float* z_atac = (const float*)d_in[1];
  const float* noise  = (const float*)d_in[2];

  float* ws = (float*)d_ws;
  float* Zr    = ws;                       // N*D
  float* Za    = Zr + NN * DD;             // N*D
  float* normA = Za + NN * DD;             // N
  int*   ridx  = (int*)(normA + NN);       // N*K
  float* rw    = (float*)(ridx + NN * KK); // N*K
  int*   aidx  = (int*)(rw + NN * KK);     // N*K
  float* aw    = (float*)(aidx + NN * KK); // N*K
  float* rvec  = aw + NN * KK;             // N
  float* va    = rvec + NN;                // N
  float* vb    = va + NN;                  // N
  float* acc   = vb + NN;                  // 16
  float* Sbase = acc + 16;

  size_t usedBytes = (size_t)(Sbase - ws) * sizeof(float);
  int B = NN;
  while (B > 64 && usedBytes + 2ull * NN * (size_t)B * sizeof(float) > ws_size) B >>= 1;
  float* S0 = Sbase;
  float* S1 = S0 + (size_t)NN * B;

  k_init<<<1, 64, 0, stream>>>(acc);
  k_norm<<<NN / 4, 256, 0, stream>>>(z_rna, Zr, normA, acc, 0);
  k_norm<<<NN / 4, 256, 0, stream>>>(z_atac, Za, normA, acc, 1);
  k_topk<<<NN / 2, 128, 0, stream>>>(Zr, ridx, rw, acc, 0);
  k_topk<<<NN / 2, 128, 0, stream>>>(Za, aidx, aw, acc, 1);
  k_edges<<<NN / 4, 256, 0, stream>>>(Za, normA, ridx, rw, aidx, aw, acc);
  k_neg<<<NN, 256, 0, stream>>>(noise, Za, ridx, acc);

  // rowsum recurrence (rowsum(A*S) = A*rowsum(S))
  k_vinit<<<NN / 256, 256, 0, stream>>>(rw, rvec, va);
  float* vc = va; float* vn = vb;
  for (int it = 0; it < 5; ++it) {
    k_vstep<<<NN / 256, 256, 0, stream>>>(vc, vn, rvec, ridx, rw);
    float* tmp = vc; vc = vn; vn = tmp;
  }
  // vc = rowsums of S_5

  for (int c0 = 0; c0 < NN; c0 += B) {
    int n4 = NN * B / 4;
    k_zero<<<(n4 + 255) / 256, 256, 0, stream>>>((float4*)S0, n4);
    k_scatter<<<NN / 4, 256, 0, stream>>>(S0, ridx, rw, c0, B);
    float* sc = S0; float* sn = S1;
    for (int it = 0; it < 5; ++it) {
      k_spmm<<<NN, 256, 0, stream>>>(sc, sn, ridx, rw, c0, B);
      float* tmp = sc; sc = sn; sn = tmp;
    }
    k_s2<<<NN, 256, 0, stream>>>(sc, vc, acc, B);
    k_cross<<<NN / 4, 256, 0, stream>>>(sc, vc, aidx, aw, acc, c0, B);
  }

  k_final<<<1, 1, 0, stream>>>(acc, (float*)d_out);
}